// Round 1
// baseline (331.492 us; speedup 1.0000x reference)
//
#include <hip/hip_runtime.h>

// LayerGCN: out = relu(bn2(relu(bn1( (D^-.5 (A>=.1) D^-.5) V @ W1 )) @ W2))
// B=4096, N=128, C_IN=64, C_HID=256, C_OUT=128. One block per batch, bf16 MFMA.

#define THRESH 0.1f
#define BN_EPS 1e-5f

typedef __attribute__((ext_vector_type(8))) short bf16x8;
typedef __attribute__((ext_vector_type(4))) float f32x4;
typedef __attribute__((ext_vector_type(4))) unsigned short u16x4;

__device__ __forceinline__ unsigned short f2bf(float f) {
    union { float f; unsigned u; } x; x.f = f;
    unsigned r = x.u + 0x7FFFu + ((x.u >> 16) & 1u);   // RNE, matches HW cvt
    return (unsigned short)(r >> 16);
}

// ---------------- prep: transpose+cast weights, fold BN ----------------
// W1t[n][k] = bf16(W1[k][n])  (256x64), W2t[n][k] = bf16(W2[k][n]) (128x256)
// sc1 = g1*rsqrt(rv1+eps); sh1 = (b1-rm1)*sc1 + be1   (same for layer 2)
__global__ void gcn_prep(const float* __restrict__ W1, const float* __restrict__ b1,
                         const float* __restrict__ g1, const float* __restrict__ be1,
                         const float* __restrict__ rm1, const float* __restrict__ rv1,
                         const float* __restrict__ W2, const float* __restrict__ b2,
                         const float* __restrict__ g2, const float* __restrict__ be2,
                         const float* __restrict__ rm2, const float* __restrict__ rv2,
                         unsigned short* __restrict__ W1t, unsigned short* __restrict__ W2t,
                         float* __restrict__ sc1, float* __restrict__ sh1,
                         float* __restrict__ sc2, float* __restrict__ sh2) {
    int t = blockIdx.x * blockDim.x + threadIdx.x;       // 0..32767
    if (t < 256 * 64) {                                  // W1t: n = t/64, k = t%64
        int n = t >> 6, k = t & 63;
        W1t[t] = f2bf(W1[k * 256 + n]);
    }
    if (t < 128 * 256) {                                 // W2t: n = t/256, k = t%256
        int n = t >> 8, k = t & 255;
        W2t[t] = f2bf(W2[k * 128 + n]);
    }
    if (t < 256) {
        float s = g1[t] * rsqrtf(rv1[t] + BN_EPS);
        sc1[t] = s;
        sh1[t] = (b1[t] - rm1[t]) * s + be1[t];
    }
    if (t < 128) {
        float s = g2[t] * rsqrtf(rv2[t] + BN_EPS);
        sc2[t] = s;
        sh2[t] = (b2[t] - rm2[t]) * s + be2[t];
    }
}

// ---------------- main fused kernel ----------------
// LDS map (bytes), total 71168:
//   s_ath : [128][136] u16 @ 0      (34816)  a_th; rows 32w..32w+31 overlaid by wave w's h after GEMM1
//   s_vtt : [64][136]  u16 @ 34816  (17408)  vt^T = (d^-.5 * v)^T           -> 52224
//   s_x1  : wave w: [32][264] u16 @ w*16896  (67584 total, overlays ath/vtt after barrier 3)
//   s_dinv @ 67584 (512) | s_sc1 @ 68096 | s_sh1 @ 69120 | s_sc2 @ 70144 | s_sh2 @ 70656
__global__ void __launch_bounds__(256, 2)
gcn_main(const float* __restrict__ A, const float* __restrict__ V,
         const unsigned short* __restrict__ W1t, const unsigned short* __restrict__ W2t,
         const float* __restrict__ sc1g, const float* __restrict__ sh1g,
         const float* __restrict__ sc2g, const float* __restrict__ sh2g,
         float* __restrict__ out) {
    __shared__ char smem[71168];
    unsigned short* s_ath = (unsigned short*)smem;            // stride 136
    unsigned short* s_vtt = (unsigned short*)(smem + 34816);  // stride 136
    float* s_dinv = (float*)(smem + 67584);
    float* s_sc1  = (float*)(smem + 68096);
    float* s_sh1  = (float*)(smem + 69120);
    float* s_sc2  = (float*)(smem + 70144);
    float* s_sh2  = (float*)(smem + 70656);

    const int t    = threadIdx.x;
    const int lane = t & 63;
    const int w    = t >> 6;       // wave 0..3, owns output rows 32w..32w+31
    const int b    = blockIdx.x;

    // stage folded BN params
    s_sc1[t] = sc1g[t];
    s_sh1[t] = sh1g[t];
    if (t < 128) { s_sc2[t] = sc2g[t]; s_sh2[t] = sh2g[t]; }

    // prefetch V tile (128x64 f32) into registers; scaled after degrees known
    const float* vb = V + (size_t)b * 8192;
    f32x4 vr[8];
#pragma unroll
    for (int i = 0; i < 8; ++i) vr[i] = *(const f32x4*)(vb + 4 * t + 1024 * i);

    // load A tile (128x128 f32), threshold -> a_th bf16, row degree -> dinv
    const float* ab = A + (size_t)b * 16384;
#pragma unroll
    for (int i = 0; i < 16; ++i) {
        f32x4 x = *(const f32x4*)(ab + 4 * t + 1024 * i);
        int row = (t >> 5) + 8 * i;        // 32 consecutive threads cover one row
        int col = (4 * t) & 127;
        u16x4 th;
        th.x = (x.x >= THRESH) ? (unsigned short)0x3F80u : (unsigned short)0u;
        th.y = (x.y >= THRESH) ? (unsigned short)0x3F80u : (unsigned short)0u;
        th.z = (x.z >= THRESH) ? (unsigned short)0x3F80u : (unsigned short)0u;
        th.w = (x.w >= THRESH) ? (unsigned short)0x3F80u : (unsigned short)0u;
        *(u16x4*)(s_ath + row * 136 + col) = th;
        int cnt = (x.x >= THRESH) + (x.y >= THRESH) + (x.z >= THRESH) + (x.w >= THRESH);
#pragma unroll
        for (int s = 1; s < 32; s <<= 1) cnt += __shfl_xor(cnt, s);   // reduce within 32-thread row group
        if ((lane & 31) == 0) s_dinv[row] = rsqrtf((float)cnt);
    }
    __syncthreads();   // (1) a_th, dinv, BN params visible

    // vt^T[c][m] = bf16(v[m][c] * dinv[m])
    {
        int m0 = t >> 4;
        int c0 = (4 * t) & 63;
#pragma unroll
        for (int i = 0; i < 8; ++i) {
            int m = m0 + 16 * i;
            float d = s_dinv[m];
            s_vtt[(c0 + 0) * 136 + m] = f2bf(vr[i].x * d);
            s_vtt[(c0 + 1) * 136 + m] = f2bf(vr[i].y * d);
            s_vtt[(c0 + 2) * 136 + m] = f2bf(vr[i].z * d);
            s_vtt[(c0 + 3) * 136 + m] = f2bf(vr[i].w * d);
        }
    }
    __syncthreads();   // (2) vt^T ready

    const int r16 = lane & 15;   // A row-in-tile / B col-in-tile / D col
    const int g   = lane >> 4;   // lane group: k-slice 8g..8g+7, D rows 4g..4g+3

    // ---- GEMM1: h(32 rows) = a_th @ vt,  M=32/wave, N=64, K=128 ----
    f32x4 acc1[2][4];
#pragma unroll
    for (int rt = 0; rt < 2; ++rt)
#pragma unroll
        for (int ct = 0; ct < 4; ++ct) acc1[rt][ct] = f32x4{0.f, 0.f, 0.f, 0.f};
#pragma unroll
    for (int ks = 0; ks < 4; ++ks) {
        bf16x8 af0 = *(const bf16x8*)(s_ath + (32 * w + r16) * 136 + ks * 32 + 8 * g);
        bf16x8 af1 = *(const bf16x8*)(s_ath + (32 * w + 16 + r16) * 136 + ks * 32 + 8 * g);
#pragma unroll
        for (int ct = 0; ct < 4; ++ct) {
            bf16x8 bf = *(const bf16x8*)(s_vtt + (ct * 16 + r16) * 136 + ks * 32 + 8 * g);
            acc1[0][ct] = __builtin_amdgcn_mfma_f32_16x16x32_bf16(af0, bf, acc1[0][ct], 0, 0, 0);
            acc1[1][ct] = __builtin_amdgcn_mfma_f32_16x16x32_bf16(af1, bf, acc1[1][ct], 0, 0, 0);
        }
    }
    // h = dinv[row] * acc -> bf16, overlaid into this wave's OWN a_th rows (cols 0..63)
#pragma unroll
    for (int rt = 0; rt < 2; ++rt)
#pragma unroll
        for (int ct = 0; ct < 4; ++ct)
#pragma unroll
            for (int r = 0; r < 4; ++r) {
                int row = 32 * w + rt * 16 + g * 4 + r;
                s_ath[row * 136 + ct * 16 + r16] = f2bf(acc1[rt][ct][r] * s_dinv[row]);
            }
    // own-wave LDS RAW: DS pipe in-order per wave; compiler inserts lgkmcnt.

    // ---- GEMM2: x1(32 rows) = h @ W1,  N=256, K=64 (B-frags from L2) ----
    f32x4 acc2[2][16];
#pragma unroll
    for (int rt = 0; rt < 2; ++rt)
#pragma unroll
        for (int ct = 0; ct < 16; ++ct) acc2[rt][ct] = f32x4{0.f, 0.f, 0.f, 0.f};
#pragma unroll
    for (int ks = 0; ks < 2; ++ks) {
        bf16x8 af0 = *(const bf16x8*)(s_ath + (32 * w + r16) * 136 + ks * 32 + 8 * g);
        bf16x8 af1 = *(const bf16x8*)(s_ath + (32 * w + 16 + r16) * 136 + ks * 32 + 8 * g);
#pragma unroll
        for (int ct = 0; ct < 16; ++ct) {
            bf16x8 bf = *(const bf16x8*)(W1t + (ct * 16 + r16) * 64 + ks * 32 + 8 * g);
            acc2[0][ct] = __builtin_amdgcn_mfma_f32_16x16x32_bf16(af0, bf, acc2[0][ct], 0, 0, 0);
            acc2[1][ct] = __builtin_amdgcn_mfma_f32_16x16x32_bf16(af1, bf, acc2[1][ct], 0, 0, 0);
        }
    }
    __syncthreads();   // (3) all waves done reading ath/vtt/h -> region reusable for x1

    // BN1 + ReLU -> x1 bf16 into wave-private region [32][264]
    unsigned short* s_x1 = (unsigned short*)(smem + w * 16896);
#pragma unroll
    for (int rt = 0; rt < 2; ++rt)
#pragma unroll
        for (int ct = 0; ct < 16; ++ct) {
            int c = ct * 16 + r16;
            float sc = s_sc1[c], sh = s_sh1[c];
#pragma unroll
            for (int r = 0; r < 4; ++r) {
                int row = rt * 16 + g * 4 + r;
                float y = fmaxf(fmaf(acc2[rt][ct][r], sc, sh), 0.f);
                s_x1[row * 264 + c] = f2bf(y);
            }
        }

    // ---- GEMM3: x2(32 rows) = x1 @ W2,  N=128, K=256 (B-frags from L2) ----
    f32x4 acc3[2][8];
#pragma unroll
    for (int rt = 0; rt < 2; ++rt)
#pragma unroll
        for (int ct = 0; ct < 8; ++ct) acc3[rt][ct] = f32x4{0.f, 0.f, 0.f, 0.f};
#pragma unroll
    for (int ks = 0; ks < 8; ++ks) {
        bf16x8 af0 = *(const bf16x8*)(s_x1 + r16 * 264 + ks * 32 + 8 * g);
        bf16x8 af1 = *(const bf16x8*)(s_x1 + (16 + r16) * 264 + ks * 32 + 8 * g);
#pragma unroll
        for (int ct = 0; ct < 8; ++ct) {
            bf16x8 bf = *(const bf16x8*)(W2t + (ct * 16 + r16) * 256 + ks * 32 + 8 * g);
            acc3[0][ct] = __builtin_amdgcn_mfma_f32_16x16x32_bf16(af0, bf, acc3[0][ct], 0, 0, 0);
            acc3[1][ct] = __builtin_amdgcn_mfma_f32_16x16x32_bf16(af1, bf, acc3[1][ct], 0, 0, 0);
        }
    }

    // BN2 + ReLU -> global (fp32)
    float* ob = out + (size_t)b * 16384;
#pragma unroll
    for (int rt = 0; rt < 2; ++rt)
#pragma unroll
        for (int ct = 0; ct < 8; ++ct) {
            int c = ct * 16 + r16;
            float sc = s_sc2[c], sh = s_sh2[c];
#pragma unroll
            for (int r = 0; r < 4; ++r) {
                int row = 32 * w + rt * 16 + g * 4 + r;
                ob[row * 128 + c] = fmaxf(fmaf(acc3[rt][ct][r], sc, sh), 0.f);
            }
        }
}

extern "C" void kernel_launch(void* const* d_in, const int* in_sizes, int n_in,
                              void* d_out, int out_size, void* d_ws, size_t ws_size,
                              hipStream_t stream) {
    (void)in_sizes; (void)n_in; (void)out_size; (void)ws_size;
    const float* a   = (const float*)d_in[0];
    const float* v   = (const float*)d_in[1];
    const float* W1  = (const float*)d_in[2];
    const float* b1  = (const float*)d_in[3];
    const float* g1  = (const float*)d_in[4];
    const float* be1 = (const float*)d_in[5];
    const float* rm1 = (const float*)d_in[6];
    const float* rv1 = (const float*)d_in[7];
    const float* W2  = (const float*)d_in[8];
    const float* b2  = (const float*)d_in[9];
    const float* g2  = (const float*)d_in[10];
    const float* be2 = (const float*)d_in[11];
    const float* rm2 = (const float*)d_in[12];
    const float* rv2 = (const float*)d_in[13];

    char* ws = (char*)d_ws;
    unsigned short* W1t = (unsigned short*)ws;             // 32768 B
    unsigned short* W2t = (unsigned short*)(ws + 32768);   // 65536 B
    float* sc1 = (float*)(ws + 98304);
    float* sh1 = (float*)(ws + 99328);
    float* sc2 = (float*)(ws + 100352);
    float* sh2 = (float*)(ws + 100864);                    // total 101376 B of ws

    gcn_prep<<<128, 256, 0, stream>>>(W1, b1, g1, be1, rm1, rv1,
                                      W2, b2, g2, be2, rm2, rv2,
                                      W1t, W2t, sc1, sh1, sc2, sh2);
    gcn_main<<<4096, 256, 0, stream>>>(a, v, W1t, W2t, sc1, sh1, sc2, sh2, (float*)d_out);
}